// Round 13
// baseline (298.627 us; speedup 1.0000x reference)
//
#include <hip/hip_runtime.h>
#include <hip/hip_bf16.h>

// GATNet v20: measurement round. v19 showed un-merging hist from gemm1
// saved nothing (merged 62 ≈ max(hist,gemm1)) and the convert cost +12.
// The top-5 profiler view only ever shows the single slowest kernel's
// instances, so ~80us of the budget is unattributed. This round:
//  - k_agg1 quartered (4 x ~17us) -> top-5 cutoff drops below every
//    remaining kernel; next profile names the true #2 with hard numbers.
//  - Ab pre-conversion reverted (gemm1 = v14 f2b-staging form, standalone).
//  - hist + W-prep in one small kernel (measurable if #2).

#define LRELU(x) ((x) > 0.f ? (x) : 0.2f * (x))

typedef __attribute__((ext_vector_type(8))) short short8;
typedef __attribute__((ext_vector_type(8))) unsigned short ushort8;
typedef __attribute__((ext_vector_type(4))) float f32x4;

__device__ inline unsigned short f2b(float f) {
    __hip_bfloat16 h = __float2bfloat16(f);
    return *reinterpret_cast<unsigned short*>(&h);
}
__device__ inline float b2f(unsigned short u) {
    __hip_bfloat16 h;
    *reinterpret_cast<unsigned short*>(&h) = u;
    return __bfloat162float(h);
}
__device__ inline float bl(unsigned int u) { return __uint_as_float(u << 16); }
__device__ inline float bh(unsigned int u) { return __uint_as_float(u & 0xffff0000u); }

// ---------------- hist + weight prep (independent branches) ----------------

__global__ __launch_bounds__(256) void k_histprep(const int* __restrict__ dst,
                                                  int* deg, int* __restrict__ pos, int E,
                                                  const float* __restrict__ W1,
                                                  const float* __restrict__ W2,
                                                  unsigned short* __restrict__ W1t,
                                                  unsigned short* __restrict__ W2t,
                                                  int HB) {
    int b = blockIdx.x;
    int t = threadIdx.x;
    if (b < HB) {
        int i = b * 256 + t;
        if (i < E) pos[i] = atomicAdd(&deg[dst[i]], 1);
    } else {
        int bb = b - HB;
        if (bb < 256) {
            int k = bb, nn = t;
            W1t[nn * 256 + k] = f2b(W1[k * 256 + nn]);
        } else {
            int nn = bb - 256, k = t;
            W2t[nn * 256 + k] = f2b(W2[k * 16 + nn]);
        }
    }
}

// ---------------- fused single-kernel scan (v15 protocol, verified) --------

__global__ __launch_bounds__(256) void k_scan(const int* __restrict__ deg,
                                              unsigned int* __restrict__ state,
                                              int* __restrict__ offs, int n, int P) {
    __shared__ int sc[256];
    __shared__ int sa[256];
    int b = blockIdx.x, t = threadIdx.x;
    int i = b * 256 + t;
    int v = (i < n) ? deg[i] + 1 : 0;   // +1: self loop
    sc[t] = v;
    __syncthreads();
    for (int off = 1; off < 256; off <<= 1) {
        int x = 0;
        if (t >= off) x = sc[t - off];
        __syncthreads();
        sc[t] += x;
        __syncthreads();
    }
    if (t == 255) {
        unsigned int pack = 0x80000000u | (unsigned int)sc[255];
        atomicExch(&state[b], pack);   // device-scope publish (flag+value, one word)
    }
    if (t < b) {
        unsigned int s;
        do {
            s = atomicAdd(&state[t], 0u);
        } while (!(s & 0x80000000u));
        sa[t] = (int)(s & 0x7fffffffu);
    } else {
        sa[t] = 0;
    }
    __syncthreads();
    for (int off = 128; off; off >>= 1) {
        if (t < off) sa[t] += sa[t + off];
        __syncthreads();
    }
    int prefix = sa[0];
    if (i < n) offs[i] = prefix + sc[t] - v;   // exclusive
    if (i == 0) offs[n] = P;
}

// ---------------- scatter (atomic-free via pos) ----------------

__global__ void k_scatter(const int* __restrict__ src, const int* __restrict__ dst,
                          const int* __restrict__ pos, const int* __restrict__ offs,
                          int* __restrict__ csr, int E, int n) {
    int i = blockIdx.x * 256 + threadIdx.x;
    if (i < E) {
        int d = dst[i];
        csr[offs[d] + pos[i]] = src[i];
    } else if (i < E + n) {
        int v = i - E;
        csr[offs[v + 1] - 1] = v;   // self loop in the last slot of row v
    }
}

// ---------------- GEMM1 (MFMA bf16) + fused layer-1 attention logits --------
// 128x128 tile, f2b staging from x (v14 structure, standalone).

__global__ __launch_bounds__(256) void k_gemm1(const float* __restrict__ A,
                                               const unsigned short* __restrict__ Wt,
                                               const float* __restrict__ asrc,
                                               const float* __restrict__ adst,
                                               unsigned short* __restrict__ h1b,
                                               float* __restrict__ als,
                                               float* __restrict__ ald, int M) {
    __shared__ unsigned short As[128][40];
    __shared__ unsigned short Bs[128][40];
    int t = threadIdx.x;
    int r0 = blockIdx.x * 128, c0 = blockIdx.y * 128;
    int srow = t >> 1, shalf = t & 1;
    int lane = t & 63, w = t >> 6;
    int lane15 = lane & 15, quad = lane >> 4;
    int rbw = (w & 1) * 64, cbw = (w >> 1) * 64;

    f32x4 acc[4][4];
#pragma unroll
    for (int i = 0; i < 4; i++)
#pragma unroll
        for (int j = 0; j < 4; j++) acc[i][j] = (f32x4)0.f;

    for (int k0 = 0; k0 < 256; k0 += 32) {
        {
            int row = r0 + srow;
            ushort8 p0, p1;
            if (row < M) {
                const float4* sp = (const float4*)&A[(size_t)row * 256 + k0 + shalf * 16];
                float4 f0 = sp[0], f1 = sp[1], f2 = sp[2], f3 = sp[3];
                p0[0] = f2b(f0.x); p0[1] = f2b(f0.y); p0[2] = f2b(f0.z); p0[3] = f2b(f0.w);
                p0[4] = f2b(f1.x); p0[5] = f2b(f1.y); p0[6] = f2b(f1.z); p0[7] = f2b(f1.w);
                p1[0] = f2b(f2.x); p1[1] = f2b(f2.y); p1[2] = f2b(f2.z); p1[3] = f2b(f2.w);
                p1[4] = f2b(f3.x); p1[5] = f2b(f3.y); p1[6] = f2b(f3.z); p1[7] = f2b(f3.w);
            } else {
                p0 = (ushort8)0; p1 = (ushort8)0;
            }
            *(ushort8*)&As[srow][shalf * 16] = p0;
            *(ushort8*)&As[srow][shalf * 16 + 8] = p1;
            const ushort8* bp = (const ushort8*)&Wt[(size_t)(c0 + srow) * 256 + k0 + shalf * 16];
            *(ushort8*)&Bs[srow][shalf * 16] = bp[0];
            *(ushort8*)&Bs[srow][shalf * 16 + 8] = bp[1];
        }
        __syncthreads();
        short8 af[4], bf[4];
#pragma unroll
        for (int i = 0; i < 4; i++)
            af[i] = *(const short8*)&As[rbw + i * 16 + lane15][quad * 8];
#pragma unroll
        for (int j = 0; j < 4; j++)
            bf[j] = *(const short8*)&Bs[cbw + j * 16 + lane15][quad * 8];
#pragma unroll
        for (int i = 0; i < 4; i++)
#pragma unroll
            for (int j = 0; j < 4; j++)
                acc[i][j] = __builtin_amdgcn_mfma_f32_16x16x32_bf16(af[i], bf[j], acc[i][j], 0, 0, 0);
        __syncthreads();
    }
    // h1b store
#pragma unroll
    for (int i = 0; i < 4; i++) {
        int rowb = r0 + rbw + i * 16 + quad * 4;
#pragma unroll
        for (int j = 0; j < 4; j++) {
            int col = c0 + cbw + j * 16 + lane15;
#pragma unroll
            for (int r = 0; r < 4; r++) {
                int row = rowb + r;
                if (row < M) h1b[(size_t)row * 256 + col] = f2b(acc[i][j][r]);
            }
        }
    }
    // fused attention logits: 2 heads per wave-col-span
    float asv[4], adv[4];
#pragma unroll
    for (int j = 0; j < 4; j++) {
        asv[j] = asrc[c0 + cbw + j * 16 + lane15];
        adv[j] = adst[c0 + cbw + j * 16 + lane15];
    }
    int hbase = (c0 + cbw) >> 5;
#pragma unroll
    for (int i = 0; i < 4; i++) {
#pragma unroll
        for (int r = 0; r < 4; r++) {
            int row = r0 + rbw + i * 16 + quad * 4 + r;
            float ps0 = acc[i][0][r] * asv[0] + acc[i][1][r] * asv[1];
            float pd0 = acc[i][0][r] * adv[0] + acc[i][1][r] * adv[1];
            float ps1 = acc[i][2][r] * asv[2] + acc[i][3][r] * asv[3];
            float pd1 = acc[i][2][r] * adv[2] + acc[i][3][r] * adv[3];
#pragma unroll
            for (int off = 1; off < 16; off <<= 1) {
                ps0 += __shfl_xor(ps0, off, 16);
                pd0 += __shfl_xor(pd0, off, 16);
                ps1 += __shfl_xor(ps1, off, 16);
                pd1 += __shfl_xor(pd1, off, 16);
            }
            if (lane15 == 0 && row < M) {
                als[(size_t)row * 8 + hbase] = ps0;
                ald[(size_t)row * 8 + hbase] = pd0;
                als[(size_t)row * 8 + hbase + 1] = ps1;
                ald[(size_t)row * 8 + hbase + 1] = pd1;
            }
        }
    }
}

// ---------------- layer-1 aggregate: self-service weights (roofline) --------
// Quartered into 4 dispatches (v0..vend) so the profiler's top-5 cutoff
// drops below every other kernel.

__global__ __launch_bounds__(256) void k_agg1(const int* __restrict__ csr,
                                              const int* __restrict__ offs,
                                              const float* __restrict__ als,
                                              const float* __restrict__ aldg,
                                              const unsigned short* __restrict__ h1b,
                                              const float* __restrict__ b1,
                                              unsigned short* __restrict__ x2b,
                                              int v0, int vend) {
    int wid = threadIdx.x >> 6;
    int v = v0 + blockIdx.x * 4 + wid;
    if (v >= vend) return;
    int lane = threadIdx.x & 63;
    int h = lane >> 3;
    int start = __builtin_amdgcn_readfirstlane(offs[v]);
    int deg = __builtin_amdgcn_readfirstlane(offs[v + 1]) - start;
    const int* __restrict__ cp = csr + start;
    int dm1 = deg - 1;
    float aldvh = aldg[(size_t)v * 8 + h];
    float a0 = 0.f, a1 = 0.f, a2 = 0.f, a3 = 0.f, wsum = 0.f;
    for (int e = 0; e < deg; e += 4) {
        int u0 = cp[e];                  // e < deg always
        int u1 = cp[min(e + 1, dm1)];
        int u2 = cp[min(e + 2, dm1)];
        int u3 = cp[min(e + 3, dm1)];
        uint2 p0 = ((const uint2*)(h1b + (size_t)u0 * 256))[lane];
        uint2 p1 = ((const uint2*)(h1b + (size_t)u1 * 256))[lane];
        uint2 p2 = ((const uint2*)(h1b + (size_t)u2 * 256))[lane];
        uint2 p3 = ((const uint2*)(h1b + (size_t)u3 * 256))[lane];
        float x0 = als[u0 * 8 + h];
        float x1 = als[u1 * 8 + h];
        float x2 = als[u2 * 8 + h];
        float x3 = als[u3 * 8 + h];
        float w0 = __expf(LRELU(x0 + aldvh));
        float w1 = __expf(LRELU(x1 + aldvh));
        float w2 = __expf(LRELU(x2 + aldvh));
        float w3 = __expf(LRELU(x3 + aldvh));
        if (e + 1 > dm1) w1 = 0.f;
        if (e + 2 > dm1) w2 = 0.f;
        if (e + 3 > dm1) w3 = 0.f;
        a0 += w0 * bl(p0.x); a1 += w0 * bh(p0.x);
        a2 += w0 * bl(p0.y); a3 += w0 * bh(p0.y);
        a0 += w1 * bl(p1.x); a1 += w1 * bh(p1.x);
        a2 += w1 * bl(p1.y); a3 += w1 * bh(p1.y);
        a0 += w2 * bl(p2.x); a1 += w2 * bh(p2.x);
        a2 += w2 * bl(p2.y); a3 += w2 * bh(p2.y);
        a0 += w3 * bl(p3.x); a1 += w3 * bh(p3.x);
        a2 += w3 * bl(p3.y); a3 += w3 * bh(p3.y);
        wsum += (w0 + w1) + (w2 + w3);
    }
    float inv = 1.0f / wsum;
    float4 bb = ((const float4*)b1)[lane];
    float o0 = fmaxf(a0 * inv + bb.x, 0.f);
    float o1 = fmaxf(a1 * inv + bb.y, 0.f);
    float o2 = fmaxf(a2 * inv + bb.z, 0.f);
    float o3 = fmaxf(a3 * inv + bb.w, 0.f);
    uint2 o;
    o.x = (unsigned int)f2b(o0) | ((unsigned int)f2b(o1) << 16);
    o.y = (unsigned int)f2b(o2) | ((unsigned int)f2b(o3) << 16);
    ((uint2*)(x2b + (size_t)v * 256))[lane] = o;
}

// ---------------- GEMM2 (MFMA) + fused layer-2 logits ----------------------

__global__ __launch_bounds__(256) void k_gemm2(const unsigned short* __restrict__ Xb,
                                               const unsigned short* __restrict__ W2t,
                                               const float* __restrict__ asrc,
                                               const float* __restrict__ adst,
                                               unsigned short* __restrict__ h2b,
                                               float* __restrict__ als,
                                               float* __restrict__ ald, int n) {
    int t = threadIdx.x;
    int lane = t & 63, w = t >> 6;
    int lane15 = lane & 15, quad = lane >> 4;
    int row0 = blockIdx.x * 64 + w * 16;
    f32x4 acc = (f32x4)0.f;
#pragma unroll
    for (int k0 = 0; k0 < 256; k0 += 32) {
        short8 a = *(const short8*)&Xb[(size_t)(row0 + lane15) * 256 + k0 + quad * 8];
        short8 b = *(const short8*)&W2t[lane15 * 256 + k0 + quad * 8];
        acc = __builtin_amdgcn_mfma_f32_16x16x32_bf16(a, b, acc, 0, 0, 0);
    }
    float asv = asrc[lane15], adv = adst[lane15];
#pragma unroll
    for (int r = 0; r < 4; r++) {
        int row = row0 + quad * 4 + r;
        float hv = acc[r];
        float ps = hv * asv, pd = hv * adv;
#pragma unroll
        for (int off = 1; off < 16; off <<= 1) {
            ps += __shfl_xor(ps, off, 16);
            pd += __shfl_xor(pd, off, 16);
        }
        if (row < n) {
            h2b[(size_t)row * 16 + lane15] = f2b(hv);
            if (lane15 == 0) {
                als[row] = ps;
                ald[row] = pd;
            }
        }
    }
}

// ---------------- layer-2 aggregate: shfl-broadcast weights -----------------

__global__ __launch_bounds__(256) void k_agg2(const int* __restrict__ csr,
                                              const int* __restrict__ offs,
                                              const float* __restrict__ als,
                                              const float* __restrict__ aldg,
                                              const unsigned short* __restrict__ h2b,
                                              const float* __restrict__ b2,
                                              float* __restrict__ out, int n) {
    int wid = threadIdx.x >> 6;
    int v = blockIdx.x * 4 + wid;
    if (v >= n) return;
    int lane = threadIdx.x & 63;
    int slot = lane & 15, cq = lane >> 4;
    int start = __builtin_amdgcn_readfirstlane(offs[v]);
    int deg = __builtin_amdgcn_readfirstlane(offs[v + 1]) - start;
    int dm1 = deg - 1;
    float aldv = aldg[v];
    float a0 = 0.f, a1 = 0.f, a2 = 0.f, a3 = 0.f, wsum = 0.f;
    for (int e = 0; e < deg; e += 32) {
        int l32 = lane & 31;
        int idx = min(e + l32, dm1);
        int uu = csr[start + idx];
        float ww = __expf(LRELU(als[uu] + aldv));
        if (e + l32 > dm1) ww = 0.f;
#pragma unroll
        for (int k = 0; k < 2; k++) {
            int sl = k * 16 + slot;
            int ue = __shfl(uu, sl, 64);
            float we = __shfl(ww, sl, 64);
            uint2 pk = ((const uint2*)(h2b + (size_t)ue * 16))[cq];
            a0 += we * bl(pk.x);
            a1 += we * bh(pk.x);
            a2 += we * bl(pk.y);
            a3 += we * bh(pk.y);
            wsum += we;
        }
    }
#pragma unroll
    for (int off = 1; off < 16; off <<= 1) {
        a0 += __shfl_xor(a0, off, 64);
        a1 += __shfl_xor(a1, off, 64);
        a2 += __shfl_xor(a2, off, 64);
        a3 += __shfl_xor(a3, off, 64);
        wsum += __shfl_xor(wsum, off, 64);
    }
    float inv = 1.0f / wsum;
    float4 bb = ((const float4*)b2)[cq];
    float o0 = a0 * inv + bb.x;
    float o1 = a1 * inv + bb.y;
    float o2 = a2 * inv + bb.z;
    float o3 = a3 * inv + bb.w;
    float mx = fmaxf(fmaxf(o0, o1), fmaxf(o2, o3));
    mx = fmaxf(mx, __shfl_xor(mx, 16, 64));
    mx = fmaxf(mx, __shfl_xor(mx, 32, 64));
    float s = __expf(o0 - mx) + __expf(o1 - mx) + __expf(o2 - mx) + __expf(o3 - mx);
    s += __shfl_xor(s, 16, 64);
    s += __shfl_xor(s, 32, 64);
    float l = mx + __logf(s);
    if (slot == 0) {
        float4 r;
        r.x = o0 - l;
        r.y = o1 - l;
        r.z = o2 - l;
        r.w = o3 - l;
        ((float4*)out)[(size_t)v * 4 + cq] = r;
    }
}

// ---------------- launch ----------------

extern "C" void kernel_launch(void* const* d_in, const int* in_sizes, int n_in,
                              void* d_out, int out_size, void* d_ws, size_t ws_size,
                              hipStream_t stream) {
    const float* x = (const float*)d_in[0];
    const int* ei = (const int*)d_in[1];
    const float* W1 = (const float*)d_in[2];
    const float* asrc1 = (const float*)d_in[3];
    const float* adst1 = (const float*)d_in[4];
    const float* b1 = (const float*)d_in[5];
    const float* W2 = (const float*)d_in[6];
    const float* asrc2 = (const float*)d_in[7];
    const float* adst2 = (const float*)d_in[8];
    const float* b2 = (const float*)d_in[9];
    float* out = (float*)d_out;

    int n = in_sizes[0] / 256;   // 50000
    int E = in_sizes[1] / 2;     // 800000
    int P = E + n;
    const int* src = ei;
    const int* dst = ei + E;
    int NB = (n + 255) / 256;
    int HB = (E + 255) / 256;    // hist blocks
    int GX = (n + 127) / 128;    // gemm1 grid x

    char* p = (char*)d_ws;
    auto alloc = [&](size_t bytes) {
        void* r = (void*)p;
        p += (bytes + 255) & ~(size_t)255;
        return r;
    };
    unsigned short* h1b = (unsigned short*)alloc((size_t)n * 256 * 2);
    unsigned short* x2b = (unsigned short*)alloc((size_t)n * 256 * 2);
    unsigned short* W1t = (unsigned short*)alloc((size_t)256 * 256 * 2);
    unsigned short* W2t = (unsigned short*)alloc((size_t)16 * 256 * 2);
    float* als1 = (float*)alloc((size_t)n * 8 * 4);
    float* ald1 = (float*)alloc((size_t)n * 8 * 4);
    unsigned short* h2b = (unsigned short*)alloc((size_t)n * 16 * 2);
    float* als2 = (float*)alloc((size_t)n * 4);
    float* ald2 = (float*)alloc((size_t)n * 4);
    int* zarea = (int*)alloc((size_t)(n + NB) * 4);   // deg[n] + scan state[NB]
    int* deg = zarea;
    unsigned int* sstate = (unsigned int*)(zarea + n);
    int* offs = (int*)alloc((size_t)(n + 1) * 4);
    int* pos = (int*)alloc((size_t)E * 4);
    int* csr = (int*)alloc((size_t)P * 4);

    hipMemsetAsync(zarea, 0, (size_t)(n + NB) * 4, stream);

    // CSR build + weight prep
    k_histprep<<<HB + 272, 256, 0, stream>>>(dst, deg, pos, E, W1, W2, W1t, W2t, HB);
    k_scan<<<NB, 256, 0, stream>>>(deg, sstate, offs, n, P);
    k_scatter<<<(P + 255) / 256, 256, 0, stream>>>(src, dst, pos, offs, csr, E, n);

    // layer 1
    k_gemm1<<<dim3(GX, 2), 256, 0, stream>>>(x, W1t, asrc1, adst1, h1b, als1, ald1, n);
    // agg1 quartered for profiling visibility
    int q = 12500;
    k_agg1<<<(q + 3) / 4, 256, 0, stream>>>(csr, offs, als1, ald1, h1b, b1, x2b, 0, q);
    k_agg1<<<(q + 3) / 4, 256, 0, stream>>>(csr, offs, als1, ald1, h1b, b1, x2b, q, 2 * q);
    k_agg1<<<(q + 3) / 4, 256, 0, stream>>>(csr, offs, als1, ald1, h1b, b1, x2b, 2 * q, 3 * q);
    k_agg1<<<(n - 3 * q + 3) / 4, 256, 0, stream>>>(csr, offs, als1, ald1, h1b, b1, x2b, 3 * q, n);

    // layer 2
    k_gemm2<<<(n + 63) / 64, 256, 0, stream>>>(x2b, W2t, asrc2, adst2, h2b, als2, ald2, n);
    k_agg2<<<(n + 3) / 4, 256, 0, stream>>>(csr, offs, als2, ald2, h2b, b2, out, n);
}

// Round 14
// 282.934 us; speedup vs baseline: 1.0555x; 1.0555x over previous
//
#include <hip/hip_runtime.h>
#include <hip/hip_bf16.h>

// GATNet v21: v17 structure + Ab fast-path gemm1. v20 measured gemm1_f2b =
// 45.5us standalone; v19<->v20 delta proves bf16-pre-converted gemm1 ~ 25us
// (f2b staging chain = ~20us). This round: convert x->Ab rides the prep
// dispatch (+12, overlapped with W-prep); gemm1 reads Ab and is merged with
// hist (v17's proven overlap; hist inferred ~38 standalone) -> merged
// ~max(25,38) ~= 40-45 vs v17's 62. Everything else = v17 (best, 274.4).

#define LRELU(x) ((x) > 0.f ? (x) : 0.2f * (x))

typedef __attribute__((ext_vector_type(8))) short short8;
typedef __attribute__((ext_vector_type(8))) unsigned short ushort8;
typedef __attribute__((ext_vector_type(4))) float f32x4;

__device__ inline unsigned short f2b(float f) {
    __hip_bfloat16 h = __float2bfloat16(f);
    return *reinterpret_cast<unsigned short*>(&h);
}
__device__ inline float b2f(unsigned short u) {
    __hip_bfloat16 h;
    *reinterpret_cast<unsigned short*>(&h) = u;
    return __bfloat162float(h);
}
__device__ inline float bl(unsigned int u) { return __uint_as_float(u << 16); }
__device__ inline float bh(unsigned int u) { return __uint_as_float(u & 0xffff0000u); }

// ---------------- prep: x->bf16 convert + weight transposes ----------------
// Blocks [0,CB): convert x to Ab (coalesced, 2048 elems/block).
// Blocks [CB,CB+272): W1t/W2t transposes.

__global__ __launch_bounds__(256) void k_prep(const float* __restrict__ x,
                                              unsigned short* __restrict__ Ab,
                                              const float* __restrict__ W1,
                                              const float* __restrict__ W2,
                                              unsigned short* __restrict__ W1t,
                                              unsigned short* __restrict__ W2t,
                                              int CB) {
    int b = blockIdx.x;
    int t = threadIdx.x;
    if (b < CB) {
        size_t base = ((size_t)b * 256 + t) * 8;
        const float4* xp = (const float4*)(x + base);
        float4 f0 = xp[0], f1 = xp[1];
        ushort8 pk;
        pk[0] = f2b(f0.x); pk[1] = f2b(f0.y); pk[2] = f2b(f0.z); pk[3] = f2b(f0.w);
        pk[4] = f2b(f1.x); pk[5] = f2b(f1.y); pk[6] = f2b(f1.z); pk[7] = f2b(f1.w);
        *(ushort8*)(Ab + base) = pk;
    } else {
        int bb = b - CB;
        if (bb < 256) {
            int k = bb, nn = t;
            W1t[nn * 256 + k] = f2b(W1[k * 256 + nn]);
        } else {
            int nn = bb - 256, k = t;
            W2t[nn * 256 + k] = f2b(W2[k * 16 + nn]);
        }
    }
}

// ---------------- fused single-kernel scan (v15 protocol, verified) --------

__global__ __launch_bounds__(256) void k_scan(const int* __restrict__ deg,
                                              unsigned int* __restrict__ state,
                                              int* __restrict__ offs, int n, int P) {
    __shared__ int sc[256];
    __shared__ int sa[256];
    int b = blockIdx.x, t = threadIdx.x;
    int i = b * 256 + t;
    int v = (i < n) ? deg[i] + 1 : 0;   // +1: self loop
    sc[t] = v;
    __syncthreads();
    for (int off = 1; off < 256; off <<= 1) {
        int x = 0;
        if (t >= off) x = sc[t - off];
        __syncthreads();
        sc[t] += x;
        __syncthreads();
    }
    if (t == 255) {
        unsigned int pack = 0x80000000u | (unsigned int)sc[255];
        atomicExch(&state[b], pack);   // device-scope publish (flag+value, one word)
    }
    if (t < b) {
        unsigned int s;
        do {
            s = atomicAdd(&state[t], 0u);
        } while (!(s & 0x80000000u));
        sa[t] = (int)(s & 0x7fffffffu);
    } else {
        sa[t] = 0;
    }
    __syncthreads();
    for (int off = 128; off; off >>= 1) {
        if (t < off) sa[t] += sa[t + off];
        __syncthreads();
    }
    int prefix = sa[0];
    if (i < n) offs[i] = prefix + sc[t] - v;   // exclusive
    if (i == 0) offs[n] = P;
}

// ---------------- scatter (atomic-free via pos) ----------------

__global__ void k_scatter(const int* __restrict__ src, const int* __restrict__ dst,
                          const int* __restrict__ pos, const int* __restrict__ offs,
                          int* __restrict__ csr, int E, int n) {
    int i = blockIdx.x * 256 + threadIdx.x;
    if (i < E) {
        int d = dst[i];
        csr[offs[d] + pos[i]] = src[i];
    } else if (i < E + n) {
        int v = i - E;
        csr[offs[v + 1] - 1] = v;   // self loop in the last slot of row v
    }
}

// ---------------- GEMM1 (bf16 Ab, MFMA, +al1 fused) MERGED with hist -------
// Blocks [0, GB): gemm1 128x128 tile; staging = plain ushort8 loads.
// Blocks [GB, GB+HB): hist (atomic deg/pos) — latency hides under gemm1.

__global__ __launch_bounds__(256) void k_gemm1h(const unsigned short* __restrict__ Ab,
                                                const unsigned short* __restrict__ Wt,
                                                const float* __restrict__ asrc,
                                                const float* __restrict__ adst,
                                                unsigned short* __restrict__ h1b,
                                                float* __restrict__ als,
                                                float* __restrict__ ald, int M,
                                                const int* __restrict__ dst,
                                                int* deg, int* __restrict__ pos,
                                                int E, int GB, int GX) {
    __shared__ unsigned short As[128][40];
    __shared__ unsigned short Bs[128][40];
    int b = blockIdx.x;
    if (b >= GB) {
        // ---- hist branch ----
        int i = (b - GB) * 256 + threadIdx.x;
        if (i < E) pos[i] = atomicAdd(&deg[dst[i]], 1);
        return;
    }
    // ---- gemm1 branch ----
    int t = threadIdx.x;
    int bx = b % GX, by = b / GX;
    int r0 = bx * 128, c0 = by * 128;
    int srow = t >> 1, shalf = t & 1;
    int lane = t & 63, w = t >> 6;
    int lane15 = lane & 15, quad = lane >> 4;
    int rbw = (w & 1) * 64, cbw = (w >> 1) * 64;

    f32x4 acc[4][4];
#pragma unroll
    for (int i = 0; i < 4; i++)
#pragma unroll
        for (int j = 0; j < 4; j++) acc[i][j] = (f32x4)0.f;

    for (int k0 = 0; k0 < 256; k0 += 32) {
        {
            int row = r0 + srow;
            ushort8 a0, a1;
            if (row < M) {
                const ushort8* ap = (const ushort8*)&Ab[(size_t)row * 256 + k0 + shalf * 16];
                a0 = ap[0];
                a1 = ap[1];
            } else {
                a0 = (ushort8)0;
                a1 = (ushort8)0;
            }
            *(ushort8*)&As[srow][shalf * 16] = a0;
            *(ushort8*)&As[srow][shalf * 16 + 8] = a1;
            const ushort8* bp = (const ushort8*)&Wt[(size_t)(c0 + srow) * 256 + k0 + shalf * 16];
            *(ushort8*)&Bs[srow][shalf * 16] = bp[0];
            *(ushort8*)&Bs[srow][shalf * 16 + 8] = bp[1];
        }
        __syncthreads();
        short8 af[4], bf[4];
#pragma unroll
        for (int i = 0; i < 4; i++)
            af[i] = *(const short8*)&As[rbw + i * 16 + lane15][quad * 8];
#pragma unroll
        for (int j = 0; j < 4; j++)
            bf[j] = *(const short8*)&Bs[cbw + j * 16 + lane15][quad * 8];
#pragma unroll
        for (int i = 0; i < 4; i++)
#pragma unroll
            for (int j = 0; j < 4; j++)
                acc[i][j] = __builtin_amdgcn_mfma_f32_16x16x32_bf16(af[i], bf[j], acc[i][j], 0, 0, 0);
        __syncthreads();
    }
    // h1b store
#pragma unroll
    for (int i = 0; i < 4; i++) {
        int rowb = r0 + rbw + i * 16 + quad * 4;
#pragma unroll
        for (int j = 0; j < 4; j++) {
            int col = c0 + cbw + j * 16 + lane15;
#pragma unroll
            for (int r = 0; r < 4; r++) {
                int row = rowb + r;
                if (row < M) h1b[(size_t)row * 256 + col] = f2b(acc[i][j][r]);
            }
        }
    }
    // fused attention logits: 2 heads per wave-col-span
    float asv[4], adv[4];
#pragma unroll
    for (int j = 0; j < 4; j++) {
        asv[j] = asrc[c0 + cbw + j * 16 + lane15];
        adv[j] = adst[c0 + cbw + j * 16 + lane15];
    }
    int hbase = (c0 + cbw) >> 5;
#pragma unroll
    for (int i = 0; i < 4; i++) {
#pragma unroll
        for (int r = 0; r < 4; r++) {
            int row = r0 + rbw + i * 16 + quad * 4 + r;
            float ps0 = acc[i][0][r] * asv[0] + acc[i][1][r] * asv[1];
            float pd0 = acc[i][0][r] * adv[0] + acc[i][1][r] * adv[1];
            float ps1 = acc[i][2][r] * asv[2] + acc[i][3][r] * asv[3];
            float pd1 = acc[i][2][r] * adv[2] + acc[i][3][r] * adv[3];
#pragma unroll
            for (int off = 1; off < 16; off <<= 1) {
                ps0 += __shfl_xor(ps0, off, 16);
                pd0 += __shfl_xor(pd0, off, 16);
                ps1 += __shfl_xor(ps1, off, 16);
                pd1 += __shfl_xor(pd1, off, 16);
            }
            if (lane15 == 0 && row < M) {
                als[(size_t)row * 8 + hbase] = ps0;
                ald[(size_t)row * 8 + hbase] = pd0;
                als[(size_t)row * 8 + hbase + 1] = ps1;
                ald[(size_t)row * 8 + hbase + 1] = pd1;
            }
        }
    }
}

// ---------------- layer-1 aggregate: self-service weights (roofline) --------
// Two half-grid dispatches (v17 form).

__global__ __launch_bounds__(256) void k_agg1(const int* __restrict__ csr,
                                              const int* __restrict__ offs,
                                              const float* __restrict__ als,
                                              const float* __restrict__ aldg,
                                              const unsigned short* __restrict__ h1b,
                                              const float* __restrict__ b1,
                                              unsigned short* __restrict__ x2b,
                                              int v0, int vend) {
    int wid = threadIdx.x >> 6;
    int v = v0 + blockIdx.x * 4 + wid;
    if (v >= vend) return;
    int lane = threadIdx.x & 63;
    int h = lane >> 3;
    int start = __builtin_amdgcn_readfirstlane(offs[v]);
    int deg = __builtin_amdgcn_readfirstlane(offs[v + 1]) - start;
    const int* __restrict__ cp = csr + start;
    int dm1 = deg - 1;
    float aldvh = aldg[(size_t)v * 8 + h];
    float a0 = 0.f, a1 = 0.f, a2 = 0.f, a3 = 0.f, wsum = 0.f;
    for (int e = 0; e < deg; e += 4) {
        int u0 = cp[e];                  // e < deg always
        int u1 = cp[min(e + 1, dm1)];
        int u2 = cp[min(e + 2, dm1)];
        int u3 = cp[min(e + 3, dm1)];
        uint2 p0 = ((const uint2*)(h1b + (size_t)u0 * 256))[lane];
        uint2 p1 = ((const uint2*)(h1b + (size_t)u1 * 256))[lane];
        uint2 p2 = ((const uint2*)(h1b + (size_t)u2 * 256))[lane];
        uint2 p3 = ((const uint2*)(h1b + (size_t)u3 * 256))[lane];
        float x0 = als[u0 * 8 + h];
        float x1 = als[u1 * 8 + h];
        float x2 = als[u2 * 8 + h];
        float x3 = als[u3 * 8 + h];
        float w0 = __expf(LRELU(x0 + aldvh));
        float w1 = __expf(LRELU(x1 + aldvh));
        float w2 = __expf(LRELU(x2 + aldvh));
        float w3 = __expf(LRELU(x3 + aldvh));
        if (e + 1 > dm1) w1 = 0.f;
        if (e + 2 > dm1) w2 = 0.f;
        if (e + 3 > dm1) w3 = 0.f;
        a0 += w0 * bl(p0.x); a1 += w0 * bh(p0.x);
        a2 += w0 * bl(p0.y); a3 += w0 * bh(p0.y);
        a0 += w1 * bl(p1.x); a1 += w1 * bh(p1.x);
        a2 += w1 * bl(p1.y); a3 += w1 * bh(p1.y);
        a0 += w2 * bl(p2.x); a1 += w2 * bh(p2.x);
        a2 += w2 * bl(p2.y); a3 += w2 * bh(p2.y);
        a0 += w3 * bl(p3.x); a1 += w3 * bh(p3.x);
        a2 += w3 * bl(p3.y); a3 += w3 * bh(p3.y);
        wsum += (w0 + w1) + (w2 + w3);
    }
    float inv = 1.0f / wsum;
    float4 bb = ((const float4*)b1)[lane];
    float o0 = fmaxf(a0 * inv + bb.x, 0.f);
    float o1 = fmaxf(a1 * inv + bb.y, 0.f);
    float o2 = fmaxf(a2 * inv + bb.z, 0.f);
    float o3 = fmaxf(a3 * inv + bb.w, 0.f);
    uint2 o;
    o.x = (unsigned int)f2b(o0) | ((unsigned int)f2b(o1) << 16);
    o.y = (unsigned int)f2b(o2) | ((unsigned int)f2b(o3) << 16);
    ((uint2*)(x2b + (size_t)v * 256))[lane] = o;
}

// ---------------- GEMM2 (MFMA) + fused layer-2 logits ----------------------

__global__ __launch_bounds__(256) void k_gemm2(const unsigned short* __restrict__ Xb,
                                               const unsigned short* __restrict__ W2t,
                                               const float* __restrict__ asrc,
                                               const float* __restrict__ adst,
                                               unsigned short* __restrict__ h2b,
                                               float* __restrict__ als,
                                               float* __restrict__ ald, int n) {
    int t = threadIdx.x;
    int lane = t & 63, w = t >> 6;
    int lane15 = lane & 15, quad = lane >> 4;
    int row0 = blockIdx.x * 64 + w * 16;
    f32x4 acc = (f32x4)0.f;
#pragma unroll
    for (int k0 = 0; k0 < 256; k0 += 32) {
        short8 a = *(const short8*)&Xb[(size_t)(row0 + lane15) * 256 + k0 + quad * 8];
        short8 b = *(const short8*)&W2t[lane15 * 256 + k0 + quad * 8];
        acc = __builtin_amdgcn_mfma_f32_16x16x32_bf16(a, b, acc, 0, 0, 0);
    }
    float asv = asrc[lane15], adv = adst[lane15];
#pragma unroll
    for (int r = 0; r < 4; r++) {
        int row = row0 + quad * 4 + r;
        float hv = acc[r];
        float ps = hv * asv, pd = hv * adv;
#pragma unroll
        for (int off = 1; off < 16; off <<= 1) {
            ps += __shfl_xor(ps, off, 16);
            pd += __shfl_xor(pd, off, 16);
        }
        if (row < n) {
            h2b[(size_t)row * 16 + lane15] = f2b(hv);
            if (lane15 == 0) {
                als[row] = ps;
                ald[row] = pd;
            }
        }
    }
}

// ---------------- layer-2 aggregate: shfl-broadcast weights -----------------

__global__ __launch_bounds__(256) void k_agg2(const int* __restrict__ csr,
                                              const int* __restrict__ offs,
                                              const float* __restrict__ als,
                                              const float* __restrict__ aldg,
                                              const unsigned short* __restrict__ h2b,
                                              const float* __restrict__ b2,
                                              float* __restrict__ out, int n) {
    int wid = threadIdx.x >> 6;
    int v = blockIdx.x * 4 + wid;
    if (v >= n) return;
    int lane = threadIdx.x & 63;
    int slot = lane & 15, cq = lane >> 4;
    int start = __builtin_amdgcn_readfirstlane(offs[v]);
    int deg = __builtin_amdgcn_readfirstlane(offs[v + 1]) - start;
    int dm1 = deg - 1;
    float aldv = aldg[v];
    float a0 = 0.f, a1 = 0.f, a2 = 0.f, a3 = 0.f, wsum = 0.f;
    for (int e = 0; e < deg; e += 32) {
        int l32 = lane & 31;
        int idx = min(e + l32, dm1);
        int uu = csr[start + idx];
        float ww = __expf(LRELU(als[uu] + aldv));
        if (e + l32 > dm1) ww = 0.f;
#pragma unroll
        for (int k = 0; k < 2; k++) {
            int sl = k * 16 + slot;
            int ue = __shfl(uu, sl, 64);
            float we = __shfl(ww, sl, 64);
            uint2 pk = ((const uint2*)(h2b + (size_t)ue * 16))[cq];
            a0 += we * bl(pk.x);
            a1 += we * bh(pk.x);
            a2 += we * bl(pk.y);
            a3 += we * bh(pk.y);
            wsum += we;
        }
    }
#pragma unroll
    for (int off = 1; off < 16; off <<= 1) {
        a0 += __shfl_xor(a0, off, 64);
        a1 += __shfl_xor(a1, off, 64);
        a2 += __shfl_xor(a2, off, 64);
        a3 += __shfl_xor(a3, off, 64);
        wsum += __shfl_xor(wsum, off, 64);
    }
    float inv = 1.0f / wsum;
    float4 bb = ((const float4*)b2)[cq];
    float o0 = a0 * inv + bb.x;
    float o1 = a1 * inv + bb.y;
    float o2 = a2 * inv + bb.z;
    float o3 = a3 * inv + bb.w;
    float mx = fmaxf(fmaxf(o0, o1), fmaxf(o2, o3));
    mx = fmaxf(mx, __shfl_xor(mx, 16, 64));
    mx = fmaxf(mx, __shfl_xor(mx, 32, 64));
    float s = __expf(o0 - mx) + __expf(o1 - mx) + __expf(o2 - mx) + __expf(o3 - mx);
    s += __shfl_xor(s, 16, 64);
    s += __shfl_xor(s, 32, 64);
    float l = mx + __logf(s);
    if (slot == 0) {
        float4 r;
        r.x = o0 - l;
        r.y = o1 - l;
        r.z = o2 - l;
        r.w = o3 - l;
        ((float4*)out)[(size_t)v * 4 + cq] = r;
    }
}

// ---------------- launch ----------------

extern "C" void kernel_launch(void* const* d_in, const int* in_sizes, int n_in,
                              void* d_out, int out_size, void* d_ws, size_t ws_size,
                              hipStream_t stream) {
    const float* x = (const float*)d_in[0];
    const int* ei = (const int*)d_in[1];
    const float* W1 = (const float*)d_in[2];
    const float* asrc1 = (const float*)d_in[3];
    const float* adst1 = (const float*)d_in[4];
    const float* b1 = (const float*)d_in[5];
    const float* W2 = (const float*)d_in[6];
    const float* asrc2 = (const float*)d_in[7];
    const float* adst2 = (const float*)d_in[8];
    const float* b2 = (const float*)d_in[9];
    float* out = (float*)d_out;

    int n = in_sizes[0] / 256;   // 50000
    int E = in_sizes[1] / 2;     // 800000
    int P = E + n;
    const int* src = ei;
    const int* dst = ei + E;
    int NB = (n + 255) / 256;
    int HB = (E + 255) / 256;    // hist blocks
    int CB = n / 8;              // convert blocks (12.8M elems / 2048)
    int GX = (n + 127) / 128;    // gemm1 grid x
    int GB = GX * 2;             // gemm1 blocks

    char* p = (char*)d_ws;
    auto alloc = [&](size_t bytes) {
        void* r = (void*)p;
        p += (bytes + 255) & ~(size_t)255;
        return r;
    };
    unsigned short* Ab = (unsigned short*)alloc((size_t)n * 256 * 2);
    unsigned short* h1b = (unsigned short*)alloc((size_t)n * 256 * 2);
    unsigned short* x2b = (unsigned short*)alloc((size_t)n * 256 * 2);
    unsigned short* W1t = (unsigned short*)alloc((size_t)256 * 256 * 2);
    unsigned short* W2t = (unsigned short*)alloc((size_t)16 * 256 * 2);
    float* als1 = (float*)alloc((size_t)n * 8 * 4);
    float* ald1 = (float*)alloc((size_t)n * 8 * 4);
    unsigned short* h2b = (unsigned short*)alloc((size_t)n * 16 * 2);
    float* als2 = (float*)alloc((size_t)n * 4);
    float* ald2 = (float*)alloc((size_t)n * 4);
    int* zarea = (int*)alloc((size_t)(n + NB) * 4);   // deg[n] + scan state[NB]
    int* deg = zarea;
    unsigned int* sstate = (unsigned int*)(zarea + n);
    int* offs = (int*)alloc((size_t)(n + 1) * 4);
    int* pos = (int*)alloc((size_t)E * 4);
    int* csr = (int*)alloc((size_t)P * 4);

    hipMemsetAsync(zarea, 0, (size_t)(n + NB) * 4, stream);

    // prep: x->bf16 + W transposes
    k_prep<<<CB + 272, 256, 0, stream>>>(x, Ab, W1, W2, W1t, W2t, CB);

    // gemm1 (Ab, +fused al1) merged with hist: atomics overlap MFMA/loads
    k_gemm1h<<<GB + HB, 256, 0, stream>>>(Ab, W1t, asrc1, adst1, h1b, als1, ald1, n,
                                          dst, deg, pos, E, GB, GX);
    k_scan<<<NB, 256, 0, stream>>>(deg, sstate, offs, n, P);
    k_scatter<<<(P + 255) / 256, 256, 0, stream>>>(src, dst, pos, offs, csr, E, n);

    // layer-1 aggregate, two halves (v17 form)
    int nh = ((n / 2) + 3) & ~3;   // 25000
    k_agg1<<<(nh + 3) / 4, 256, 0, stream>>>(csr, offs, als1, ald1, h1b, b1, x2b, 0, nh);
    k_agg1<<<(n - nh + 3) / 4, 256, 0, stream>>>(csr, offs, als1, ald1, h1b, b1, x2b, nh, n);

    // layer 2
    k_gemm2<<<(n + 63) / 64, 256, 0, stream>>>(x2b, W2t, asrc2, adst2, h2b, als2, ald2, n);
    k_agg2<<<(n + 3) / 4, 256, 0, stream>>>(csr, offs, als2, ald2, h2b, b2, out, n);
}

// Round 15
// 262.047 us; speedup vs baseline: 1.1396x; 1.0797x over previous
//
#include <hip/hip_runtime.h>
#include <hip/hip_bf16.h>

// GATNet v22: atomic-free CSR build via 2-level bucket counting sort.
// Rounds 10-14 proved the 800k global atomic-return histogram is a ~40-60us
// invariant monster (contention/occupancy/merge all falsified). dst,src <
// 65536 -> edge packs into u32. Build: LDS-binned bucket count (dst>>8, 196
// bins) -> tiny scan -> bucket scatter (merged with gemm1-Ab) -> per-bucket
// LDS counting sort (dst&255) emitting offs+csr. Deletes deg/pos/spin-scan/
// random-RMW scatter. agg1 (67.5 roofline) / gemm2 / agg2 unchanged.

#define LRELU(x) ((x) > 0.f ? (x) : 0.2f * (x))

typedef __attribute__((ext_vector_type(8))) short short8;
typedef __attribute__((ext_vector_type(8))) unsigned short ushort8;
typedef __attribute__((ext_vector_type(4))) float f32x4;

__device__ inline unsigned short f2b(float f) {
    __hip_bfloat16 h = __float2bfloat16(f);
    return *reinterpret_cast<unsigned short*>(&h);
}
__device__ inline float b2f(unsigned short u) {
    __hip_bfloat16 h;
    *reinterpret_cast<unsigned short*>(&h) = u;
    return __bfloat162float(h);
}
__device__ inline float bl(unsigned int u) { return __uint_as_float(u << 16); }
__device__ inline float bh(unsigned int u) { return __uint_as_float(u & 0xffff0000u); }

#define BCB 256   // bucket-count/scatter blocks

// ---------------- prep: x->bf16 ∥ bucket-count ∥ W transposes --------------
// Blocks [0,CB): convert. [CB,CB+BCB): LDS-hist bucket count (dst>>8).
// [CB+BCB, +272): W1t/W2t.

__global__ __launch_bounds__(256) void k_prep(const float* __restrict__ x,
                                              unsigned short* __restrict__ Ab,
                                              const int* __restrict__ src,
                                              const int* __restrict__ dst,
                                              int E, int n, int NBK,
                                              int* __restrict__ gcnt,
                                              const float* __restrict__ W1,
                                              const float* __restrict__ W2,
                                              unsigned short* __restrict__ W1t,
                                              unsigned short* __restrict__ W2t,
                                              int CB) {
    __shared__ int lh[256];
    int b = blockIdx.x;
    int t = threadIdx.x;
    if (b < CB) {
        size_t base = ((size_t)b * 256 + t) * 8;
        const float4* xp = (const float4*)(x + base);
        float4 f0 = xp[0], f1 = xp[1];
        ushort8 pk;
        pk[0] = f2b(f0.x); pk[1] = f2b(f0.y); pk[2] = f2b(f0.z); pk[3] = f2b(f0.w);
        pk[4] = f2b(f1.x); pk[5] = f2b(f1.y); pk[6] = f2b(f1.z); pk[7] = f2b(f1.w);
        *(ushort8*)(Ab + base) = pk;
    } else if (b < CB + BCB) {
        int bb = b - CB;
        lh[t] = 0;
        __syncthreads();
        int P = E + n;
        for (int i = bb * 256 + t; i < P; i += BCB * 256) {
            int d = (i < E) ? dst[i] : (i - E);
            atomicAdd(&lh[d >> 8], 1);
        }
        __syncthreads();
        if (t < NBK && lh[t]) atomicAdd(&gcnt[t], lh[t]);
    } else {
        int bb = b - CB - BCB;
        if (bb < 256) {
            int k = bb, nn = t;
            W1t[nn * 256 + k] = f2b(W1[k * 256 + nn]);
        } else {
            int nn = bb - 256, k = t;
            W2t[nn * 256 + k] = f2b(W2[k * 16 + nn]);
        }
    }
}

// ---------------- bucket scan (1 block over NBK=196 totals) ----------------

__global__ __launch_bounds__(256) void k_bscan(const int* __restrict__ gcnt,
                                               int* __restrict__ boffs,
                                               int* __restrict__ cursor,
                                               int* __restrict__ offs,
                                               int n, int P, int NBK) {
    __shared__ int sc[256];
    int t = threadIdx.x;
    int v = (t < NBK) ? gcnt[t] : 0;
    sc[t] = v;
    __syncthreads();
    for (int off = 1; off < 256; off <<= 1) {
        int xv = 0;
        if (t >= off) xv = sc[t - off];
        __syncthreads();
        sc[t] += xv;
        __syncthreads();
    }
    if (t < NBK) {
        int ex = sc[t] - v;
        boffs[t] = ex;
        cursor[t] = ex;
    }
    if (t == 0) {
        boffs[NBK] = P;
        offs[n] = P;
    }
}

// ---------------- GEMM1 (bf16 Ab + fused al1) ∥ bucket-scatter -------------
// Blocks [0,GB): gemm1 128x128 tile. [GB,GB+BCB): scatter packed edges into
// dst>>8 buckets (LDS count -> reserve chunk -> LDS-slotted write).

__global__ __launch_bounds__(256) void k_gemm1sc(const unsigned short* __restrict__ Ab,
                                                 const unsigned short* __restrict__ Wt,
                                                 const float* __restrict__ asrc,
                                                 const float* __restrict__ adst,
                                                 unsigned short* __restrict__ h1b,
                                                 float* __restrict__ als,
                                                 float* __restrict__ ald, int M,
                                                 const int* __restrict__ src,
                                                 const int* __restrict__ dst,
                                                 int E, int NBK,
                                                 int* __restrict__ cursor,
                                                 unsigned int* __restrict__ ebuf,
                                                 int GB, int GX) {
    __shared__ unsigned short As[128][40];
    __shared__ unsigned short Bs[128][40];
    __shared__ int lh[256];
    __shared__ int lbase[256];
    int b = blockIdx.x;
    int t = threadIdx.x;
    if (b >= GB) {
        // ---- bucket-scatter branch ----
        int bb = b - GB;
        int P = E + M;
        lh[t] = 0;
        __syncthreads();
        for (int i = bb * 256 + t; i < P; i += BCB * 256) {
            int d = (i < E) ? dst[i] : (i - E);
            atomicAdd(&lh[d >> 8], 1);
        }
        __syncthreads();
        if (t < NBK) {
            lbase[t] = lh[t] ? atomicAdd(&cursor[t], lh[t]) : 0;
            lh[t] = 0;
        }
        __syncthreads();
        for (int i = bb * 256 + t; i < P; i += BCB * 256) {
            int d, s;
            if (i < E) {
                d = dst[i];
                s = src[i];
            } else {
                d = i - E;
                s = d;
            }
            int j = d >> 8;
            int slot = atomicAdd(&lh[j], 1);
            ebuf[lbase[j] + slot] = ((unsigned int)d << 16) | (unsigned int)s;
        }
        return;
    }
    // ---- gemm1 branch (bf16 Ab staging) ----
    int bx = b % GX, by = b / GX;
    int r0 = bx * 128, c0 = by * 128;
    int srow = t >> 1, shalf = t & 1;
    int lane = t & 63, w = t >> 6;
    int lane15 = lane & 15, quad = lane >> 4;
    int rbw = (w & 1) * 64, cbw = (w >> 1) * 64;

    f32x4 acc[4][4];
#pragma unroll
    for (int i = 0; i < 4; i++)
#pragma unroll
        for (int j = 0; j < 4; j++) acc[i][j] = (f32x4)0.f;

    for (int k0 = 0; k0 < 256; k0 += 32) {
        {
            int row = r0 + srow;
            ushort8 a0, a1;
            if (row < M) {
                const ushort8* ap = (const ushort8*)&Ab[(size_t)row * 256 + k0 + shalf * 16];
                a0 = ap[0];
                a1 = ap[1];
            } else {
                a0 = (ushort8)0;
                a1 = (ushort8)0;
            }
            *(ushort8*)&As[srow][shalf * 16] = a0;
            *(ushort8*)&As[srow][shalf * 16 + 8] = a1;
            const ushort8* bp = (const ushort8*)&Wt[(size_t)(c0 + srow) * 256 + k0 + shalf * 16];
            *(ushort8*)&Bs[srow][shalf * 16] = bp[0];
            *(ushort8*)&Bs[srow][shalf * 16 + 8] = bp[1];
        }
        __syncthreads();
        short8 af[4], bf[4];
#pragma unroll
        for (int i = 0; i < 4; i++)
            af[i] = *(const short8*)&As[rbw + i * 16 + lane15][quad * 8];
#pragma unroll
        for (int j = 0; j < 4; j++)
            bf[j] = *(const short8*)&Bs[cbw + j * 16 + lane15][quad * 8];
#pragma unroll
        for (int i = 0; i < 4; i++)
#pragma unroll
            for (int j = 0; j < 4; j++)
                acc[i][j] = __builtin_amdgcn_mfma_f32_16x16x32_bf16(af[i], bf[j], acc[i][j], 0, 0, 0);
        __syncthreads();
    }
    // h1b store
#pragma unroll
    for (int i = 0; i < 4; i++) {
        int rowb = r0 + rbw + i * 16 + quad * 4;
#pragma unroll
        for (int j = 0; j < 4; j++) {
            int col = c0 + cbw + j * 16 + lane15;
#pragma unroll
            for (int r = 0; r < 4; r++) {
                int row = rowb + r;
                if (row < M) h1b[(size_t)row * 256 + col] = f2b(acc[i][j][r]);
            }
        }
    }
    // fused attention logits: 2 heads per wave-col-span
    float asv[4], adv[4];
#pragma unroll
    for (int j = 0; j < 4; j++) {
        asv[j] = asrc[c0 + cbw + j * 16 + lane15];
        adv[j] = adst[c0 + cbw + j * 16 + lane15];
    }
    int hbase = (c0 + cbw) >> 5;
#pragma unroll
    for (int i = 0; i < 4; i++) {
#pragma unroll
        for (int r = 0; r < 4; r++) {
            int row = r0 + rbw + i * 16 + quad * 4 + r;
            float ps0 = acc[i][0][r] * asv[0] + acc[i][1][r] * asv[1];
            float pd0 = acc[i][0][r] * adv[0] + acc[i][1][r] * adv[1];
            float ps1 = acc[i][2][r] * asv[2] + acc[i][3][r] * asv[3];
            float pd1 = acc[i][2][r] * adv[2] + acc[i][3][r] * adv[3];
#pragma unroll
            for (int off = 1; off < 16; off <<= 1) {
                ps0 += __shfl_xor(ps0, off, 16);
                pd0 += __shfl_xor(pd0, off, 16);
                ps1 += __shfl_xor(ps1, off, 16);
                pd1 += __shfl_xor(pd1, off, 16);
            }
            if (lane15 == 0 && row < M) {
                als[(size_t)row * 8 + hbase] = ps0;
                ald[(size_t)row * 8 + hbase] = pd0;
                als[(size_t)row * 8 + hbase + 1] = ps1;
                ald[(size_t)row * 8 + hbase + 1] = pd1;
            }
        }
    }
}

// ---------------- per-bucket counting sort -> offs + csr -------------------
// Block j handles bucket j (dst in [256j, 256j+256)): LDS 256-bin hist +
// scan over dst&255 -> offs[v] for its 256 nodes, csr writes (dst-ordered).

__global__ __launch_bounds__(256) void k_bsort(const unsigned int* __restrict__ ebuf,
                                               const int* __restrict__ boffs,
                                               int* __restrict__ csr,
                                               int* __restrict__ offs, int n) {
    __shared__ int lh[256];
    __shared__ int sc[256];
    int j = blockIdx.x, t = threadIdx.x;
    int lo = boffs[j], hi = boffs[j + 1];
    lh[t] = 0;
    __syncthreads();
    for (int i = lo + t; i < hi; i += 256)
        atomicAdd(&lh[(ebuf[i] >> 16) & 255], 1);
    __syncthreads();
    int cnt = lh[t];
    sc[t] = cnt;
    __syncthreads();
    for (int off = 1; off < 256; off <<= 1) {
        int xv = 0;
        if (t >= off) xv = sc[t - off];
        __syncthreads();
        sc[t] += xv;
        __syncthreads();
    }
    int excl = sc[t] - cnt;         // exclusive scan (own index, post-sync)
    int v = j * 256 + t;
    if (v < n) offs[v] = lo + excl;
    lh[t] = 0;                       // reuse as per-bin cursor
    __syncthreads();
    sc[t] = excl;                    // publish exclusive offsets
    __syncthreads();
    for (int i = lo + t; i < hi; i += 256) {
        unsigned int e = ebuf[i];
        int bin = (e >> 16) & 255;
        int slot = atomicAdd(&lh[bin], 1);
        csr[lo + sc[bin] + slot] = (int)(e & 0xffffu);
    }
}

// ---------------- layer-1 aggregate: self-service weights (roofline) --------

__global__ __launch_bounds__(256) void k_agg1(const int* __restrict__ csr,
                                              const int* __restrict__ offs,
                                              const float* __restrict__ als,
                                              const float* __restrict__ aldg,
                                              const unsigned short* __restrict__ h1b,
                                              const float* __restrict__ b1,
                                              unsigned short* __restrict__ x2b, int n) {
    int wid = threadIdx.x >> 6;
    int v = blockIdx.x * 4 + wid;
    if (v >= n) return;
    int lane = threadIdx.x & 63;
    int h = lane >> 3;
    int start = __builtin_amdgcn_readfirstlane(offs[v]);
    int deg = __builtin_amdgcn_readfirstlane(offs[v + 1]) - start;
    const int* __restrict__ cp = csr + start;
    int dm1 = deg - 1;
    float aldvh = aldg[(size_t)v * 8 + h];
    float a0 = 0.f, a1 = 0.f, a2 = 0.f, a3 = 0.f, wsum = 0.f;
    for (int e = 0; e < deg; e += 4) {
        int u0 = cp[e];                  // e < deg always
        int u1 = cp[min(e + 1, dm1)];
        int u2 = cp[min(e + 2, dm1)];
        int u3 = cp[min(e + 3, dm1)];
        uint2 p0 = ((const uint2*)(h1b + (size_t)u0 * 256))[lane];
        uint2 p1 = ((const uint2*)(h1b + (size_t)u1 * 256))[lane];
        uint2 p2 = ((const uint2*)(h1b + (size_t)u2 * 256))[lane];
        uint2 p3 = ((const uint2*)(h1b + (size_t)u3 * 256))[lane];
        float x0 = als[u0 * 8 + h];
        float x1 = als[u1 * 8 + h];
        float x2 = als[u2 * 8 + h];
        float x3 = als[u3 * 8 + h];
        float w0 = __expf(LRELU(x0 + aldvh));
        float w1 = __expf(LRELU(x1 + aldvh));
        float w2 = __expf(LRELU(x2 + aldvh));
        float w3 = __expf(LRELU(x3 + aldvh));
        if (e + 1 > dm1) w1 = 0.f;
        if (e + 2 > dm1) w2 = 0.f;
        if (e + 3 > dm1) w3 = 0.f;
        a0 += w0 * bl(p0.x); a1 += w0 * bh(p0.x);
        a2 += w0 * bl(p0.y); a3 += w0 * bh(p0.y);
        a0 += w1 * bl(p1.x); a1 += w1 * bh(p1.x);
        a2 += w1 * bl(p1.y); a3 += w1 * bh(p1.y);
        a0 += w2 * bl(p2.x); a1 += w2 * bh(p2.x);
        a2 += w2 * bl(p2.y); a3 += w2 * bh(p2.y);
        a0 += w3 * bl(p3.x); a1 += w3 * bh(p3.x);
        a2 += w3 * bl(p3.y); a3 += w3 * bh(p3.y);
        wsum += (w0 + w1) + (w2 + w3);
    }
    float inv = 1.0f / wsum;
    float4 bb = ((const float4*)b1)[lane];
    float o0 = fmaxf(a0 * inv + bb.x, 0.f);
    float o1 = fmaxf(a1 * inv + bb.y, 0.f);
    float o2 = fmaxf(a2 * inv + bb.z, 0.f);
    float o3 = fmaxf(a3 * inv + bb.w, 0.f);
    uint2 o;
    o.x = (unsigned int)f2b(o0) | ((unsigned int)f2b(o1) << 16);
    o.y = (unsigned int)f2b(o2) | ((unsigned int)f2b(o3) << 16);
    ((uint2*)(x2b + (size_t)v * 256))[lane] = o;
}

// ---------------- GEMM2 (MFMA) + fused layer-2 logits ----------------------

__global__ __launch_bounds__(256) void k_gemm2(const unsigned short* __restrict__ Xb,
                                               const unsigned short* __restrict__ W2t,
                                               const float* __restrict__ asrc,
                                               const float* __restrict__ adst,
                                               unsigned short* __restrict__ h2b,
                                               float* __restrict__ als,
                                               float* __restrict__ ald, int n) {
    int t = threadIdx.x;
    int lane = t & 63, w = t >> 6;
    int lane15 = lane & 15, quad = lane >> 4;
    int row0 = blockIdx.x * 64 + w * 16;
    f32x4 acc = (f32x4)0.f;
#pragma unroll
    for (int k0 = 0; k0 < 256; k0 += 32) {
        short8 a = *(const short8*)&Xb[(size_t)(row0 + lane15) * 256 + k0 + quad * 8];
        short8 b = *(const short8*)&W2t[lane15 * 256 + k0 + quad * 8];
        acc = __builtin_amdgcn_mfma_f32_16x16x32_bf16(a, b, acc, 0, 0, 0);
    }
    float asv = asrc[lane15], adv = adst[lane15];
#pragma unroll
    for (int r = 0; r < 4; r++) {
        int row = row0 + quad * 4 + r;
        float hv = acc[r];
        float ps = hv * asv, pd = hv * adv;
#pragma unroll
        for (int off = 1; off < 16; off <<= 1) {
            ps += __shfl_xor(ps, off, 16);
            pd += __shfl_xor(pd, off, 16);
        }
        if (row < n) {
            h2b[(size_t)row * 16 + lane15] = f2b(hv);
            if (lane15 == 0) {
                als[row] = ps;
                ald[row] = pd;
            }
        }
    }
}

// ---------------- layer-2 aggregate: shfl-broadcast weights -----------------

__global__ __launch_bounds__(256) void k_agg2(const int* __restrict__ csr,
                                              const int* __restrict__ offs,
                                              const float* __restrict__ als,
                                              const float* __restrict__ aldg,
                                              const unsigned short* __restrict__ h2b,
                                              const float* __restrict__ b2,
                                              float* __restrict__ out, int n) {
    int wid = threadIdx.x >> 6;
    int v = blockIdx.x * 4 + wid;
    if (v >= n) return;
    int lane = threadIdx.x & 63;
    int slot = lane & 15, cq = lane >> 4;
    int start = __builtin_amdgcn_readfirstlane(offs[v]);
    int deg = __builtin_amdgcn_readfirstlane(offs[v + 1]) - start;
    int dm1 = deg - 1;
    float aldv = aldg[v];
    float a0 = 0.f, a1 = 0.f, a2 = 0.f, a3 = 0.f, wsum = 0.f;
    for (int e = 0; e < deg; e += 32) {
        int l32 = lane & 31;
        int idx = min(e + l32, dm1);
        int uu = csr[start + idx];
        float ww = __expf(LRELU(als[uu] + aldv));
        if (e + l32 > dm1) ww = 0.f;
#pragma unroll
        for (int k = 0; k < 2; k++) {
            int sl = k * 16 + slot;
            int ue = __shfl(uu, sl, 64);
            float we = __shfl(ww, sl, 64);
            uint2 pk = ((const uint2*)(h2b + (size_t)ue * 16))[cq];
            a0 += we * bl(pk.x);
            a1 += we * bh(pk.x);
            a2 += we * bl(pk.y);
            a3 += we * bh(pk.y);
            wsum += we;
        }
    }
#pragma unroll
    for (int off = 1; off < 16; off <<= 1) {
        a0 += __shfl_xor(a0, off, 64);
        a1 += __shfl_xor(a1, off, 64);
        a2 += __shfl_xor(a2, off, 64);
        a3 += __shfl_xor(a3, off, 64);
        wsum += __shfl_xor(wsum, off, 64);
    }
    float inv = 1.0f / wsum;
    float4 bb = ((const float4*)b2)[cq];
    float o0 = a0 * inv + bb.x;
    float o1 = a1 * inv + bb.y;
    float o2 = a2 * inv + bb.z;
    float o3 = a3 * inv + bb.w;
    float mx = fmaxf(fmaxf(o0, o1), fmaxf(o2, o3));
    mx = fmaxf(mx, __shfl_xor(mx, 16, 64));
    mx = fmaxf(mx, __shfl_xor(mx, 32, 64));
    float s = __expf(o0 - mx) + __expf(o1 - mx) + __expf(o2 - mx) + __expf(o3 - mx);
    s += __shfl_xor(s, 16, 64);
    s += __shfl_xor(s, 32, 64);
    float l = mx + __logf(s);
    if (slot == 0) {
        float4 r;
        r.x = o0 - l;
        r.y = o1 - l;
        r.z = o2 - l;
        r.w = o3 - l;
        ((float4*)out)[(size_t)v * 4 + cq] = r;
    }
}

// ---------------- launch ----------------

extern "C" void kernel_launch(void* const* d_in, const int* in_sizes, int n_in,
                              void* d_out, int out_size, void* d_ws, size_t ws_size,
                              hipStream_t stream) {
    const float* x = (const float*)d_in[0];
    const int* ei = (const int*)d_in[1];
    const float* W1 = (const float*)d_in[2];
    const float* asrc1 = (const float*)d_in[3];
    const float* adst1 = (const float*)d_in[4];
    const float* b1 = (const float*)d_in[5];
    const float* W2 = (const float*)d_in[6];
    const float* asrc2 = (const float*)d_in[7];
    const float* adst2 = (const float*)d_in[8];
    const float* b2 = (const float*)d_in[9];
    float* out = (float*)d_out;

    int n = in_sizes[0] / 256;   // 50000
    int E = in_sizes[1] / 2;     // 800000
    int P = E + n;
    const int* src = ei;
    const int* dst = ei + E;
    int NBK = (n + 255) / 256;   // 196 buckets
    int CB = n / 8;              // convert blocks (12.8M elems / 2048)
    int GX = (n + 127) / 128;    // gemm1 grid x
    int GB = GX * 2;             // gemm1 blocks

    char* p = (char*)d_ws;
    auto alloc = [&](size_t bytes) {
        void* r = (void*)p;
        p += (bytes + 255) & ~(size_t)255;
        return r;
    };
    unsigned short* Ab = (unsigned short*)alloc((size_t)n * 256 * 2);
    unsigned short* h1b = (unsigned short*)alloc((size_t)n * 256 * 2);
    unsigned short* x2b = (unsigned short*)alloc((size_t)n * 256 * 2);
    unsigned short* W1t = (unsigned short*)alloc((size_t)256 * 256 * 2);
    unsigned short* W2t = (unsigned short*)alloc((size_t)16 * 256 * 2);
    float* als1 = (float*)alloc((size_t)n * 8 * 4);
    float* ald1 = (float*)alloc((size_t)n * 8 * 4);
    unsigned short* h2b = (unsigned short*)alloc((size_t)n * 16 * 2);
    float* als2 = (float*)alloc((size_t)n * 4);
    float* ald2 = (float*)alloc((size_t)n * 4);
    int* gcnt = (int*)alloc((size_t)(NBK + 1) * 4);
    int* boffs = (int*)alloc((size_t)(NBK + 1) * 4);
    int* cursor = (int*)alloc((size_t)NBK * 4);
    int* offs = (int*)alloc((size_t)(n + 1) * 4);
    unsigned int* ebuf = (unsigned int*)alloc((size_t)P * 4);
    int* csr = (int*)alloc((size_t)P * 4);

    hipMemsetAsync(gcnt, 0, (size_t)NBK * 4, stream);

    // prep: x->bf16 ∥ bucket-count ∥ W transposes
    k_prep<<<CB + BCB + 272, 256, 0, stream>>>(x, Ab, src, dst, E, n, NBK, gcnt,
                                               W1, W2, W1t, W2t, CB);
    k_bscan<<<1, 256, 0, stream>>>(gcnt, boffs, cursor, offs, n, P, NBK);

    // gemm1 (Ab, +fused al1) ∥ bucket-scatter
    k_gemm1sc<<<GB + BCB, 256, 0, stream>>>(Ab, W1t, asrc1, adst1, h1b, als1, ald1, n,
                                            src, dst, E, NBK, cursor, ebuf, GB, GX);
    // per-bucket counting sort -> offs + csr
    k_bsort<<<NBK, 256, 0, stream>>>(ebuf, boffs, csr, offs, n);

    // layer-1 aggregate
    k_agg1<<<(n + 3) / 4, 256, 0, stream>>>(csr, offs, als1, ald1, h1b, b1, x2b, n);

    // layer 2
    k_gemm2<<<(n + 63) / 64, 256, 0, stream>>>(x2b, W2t, asrc2, adst2, h2b, als2, ald2, n);
    k_agg2<<<(n + 3) / 4, 256, 0, stream>>>(csr, offs, als2, ald2, h2b, b2, out, n);
}